// Round 1
// baseline (8373.177 us; speedup 1.0000x reference)
//
#include <hip/hip_runtime.h>

// Criterion_BiNet: multi-scale dice pyramid + monotonicity + offset L1.
// Strategy: everything reduces to 109 scalars.
//   slots[(pair*6+scale)*3 + {0,1,2}] = {sum(pp*tt), sum(pp), sum(tt)}
//   slot 108 = monotonicity sum.
// Double avg-pool per axis == single clipped-triangle conv per axis (exact,
// incl. boundary truncation between the two pools; axes factorize).

#define DIMB 4
#define DIMD 28
#define DIMH 160
#define DIMW 160
#define VOL_N (DIMB * DIMD * DIMH * DIMW)   // 2,867,200
#define GRID_R 512
#define NSLOTS 109
#define DICE_EPS 1e-7

// Generic clipped-triangle 1D conv along an axis of length L with stride S.
// k = pool size (odd). Equivalent to two stride-1 zero-pad avg pools (each /k).
__global__ void tri_conv(const float* __restrict__ in, float* __restrict__ out,
                         int N, int L, int S, int k, float inv_k2)
{
    int i = blockIdx.x * blockDim.x + threadIdx.x;
    if (i >= N) return;
    int pos  = (i / S) % L;
    int base = i - pos * S;
    int r  = k >> 1;
    int m0 = max(-r, -pos);
    int m1 = min(r, L - 1 - pos);
    int jlo = max(0, pos + m0 - r);
    int jhi = min(L - 1, pos + m1 + r);
    float acc = 0.f;
    for (int j = jlo; j <= jhi; ++j) {
        int d = j - pos;
        int cnt = min(m1, d + r) - max(m0, d - r) + 1;
        acc += (float)cnt * in[base + j * S];
    }
    out[i] = acc * inv_k2;
}

// Fused W-axis clipped-triangle conv on both volumes + 3-way reduction.
// Writes per-block partials (no atomics). Launch with exactly GRID_R blocks.
__global__ void reduce_w(const float* __restrict__ P, const float* __restrict__ T,
                         int k, float inv_k2, double* __restrict__ partials,
                         int slot_base)
{
    const int L = DIMW;
    const int r = k >> 1;
    double accI = 0.0, accP = 0.0, accT = 0.0;
    for (int i = blockIdx.x * blockDim.x + threadIdx.x; i < VOL_N;
         i += GRID_R * blockDim.x) {
        int pos  = i % L;
        int base = i - pos;
        int m0 = max(-r, -pos);
        int m1 = min(r, L - 1 - pos);
        int jlo = max(0, pos + m0 - r);
        int jhi = min(L - 1, pos + m1 + r);
        float p = 0.f, t = 0.f;
        for (int j = jlo; j <= jhi; ++j) {
            int d = j - pos;
            float w = (float)(min(m1, d + r) - max(m0, d - r) + 1) * inv_k2;
            p += w * P[base + j];
            t += w * T[base + j];
        }
        accI += (double)(p * t);
        accP += (double)p;
        accT += (double)t;
    }
    __shared__ double sI[256], sP[256], sT[256];
    int tid = threadIdx.x;
    sI[tid] = accI; sP[tid] = accP; sT[tid] = accT;
    __syncthreads();
    for (int off = 128; off > 0; off >>= 1) {
        if (tid < off) {
            sI[tid] += sI[tid + off];
            sP[tid] += sP[tid + off];
            sT[tid] += sT[tid + off];
        }
        __syncthreads();
    }
    if (tid == 0) {
        partials[(slot_base + 0) * GRID_R + blockIdx.x] = sI[0];
        partials[(slot_base + 1) * GRID_R + blockIdx.x] = sP[0];
        partials[(slot_base + 2) * GRID_R + blockIdx.x] = sT[0];
    }
}

// Temporal monotonicity: sum over b, c in [0,5), dhw of |d| - d,
// d = out[b,c+1,:] - out[b,c,:].
__global__ void mono_reduce(const float* __restrict__ out6,
                            double* __restrict__ partials)
{
    const int DHW = DIMD * DIMH * DIMW;        // 716,800
    const int N   = DIMB * 5 * DHW;            // 14,336,000
    double acc = 0.0;
    for (int i = blockIdx.x * blockDim.x + threadIdx.x; i < N;
         i += GRID_R * blockDim.x) {
        int rest = i % DHW;
        int t    = i / DHW;
        int c    = t % 5;
        int b    = t / 5;
        const float* bp = out6 + (size_t)(b * 6 + c) * DHW + rest;
        float a  = bp[0];
        float nv = bp[DHW];
        float d  = nv - a;
        acc += (double)(fabsf(d) - d);
    }
    __shared__ double s[256];
    int tid = threadIdx.x;
    s[tid] = acc;
    __syncthreads();
    for (int off = 128; off > 0; off >>= 1) {
        if (tid < off) s[tid] += s[tid + off];
        __syncthreads();
    }
    if (tid == 0) partials[108 * GRID_R + blockIdx.x] = s[0];
}

__global__ void finalize(const double* __restrict__ partials,
                         const float* __restrict__ off_a,
                         const float* __restrict__ off_b,
                         const float* __restrict__ off_ta,
                         const float* __restrict__ off_tb,
                         float* __restrict__ out)
{
    __shared__ double sums[NSLOTS];
    int t = threadIdx.x;
    for (int s = t; s < NSLOTS; s += blockDim.x) {
        double a = 0.0;
        for (int g = 0; g < GRID_R; ++g) a += partials[s * GRID_R + g];
        sums[s] = a;
    }
    __syncthreads();
    if (t == 0) {
        double loss = 0.0;
        for (int ps = 0; ps < 36; ++ps) {
            double inter = sums[ps * 3 + 0];
            double sp    = sums[ps * 3 + 1];
            double st    = sums[ps * 3 + 2];
            double dice  = 1.0 - (2.0 * inter) / (sp + st + DICE_EPS);
            loss += 0.2 * dice / 6.0;
        }
        loss += 0.1 * (sums[108] / (double)VOL_N);
        double oa = 0.0, ob = 0.0;
        for (int i = 0; i < 12; ++i) {
            oa += fabs((double)off_a[i] - (double)off_ta[i]);
            ob += fabs((double)off_b[i] - (double)off_tb[i]);
        }
        loss += 0.1 * (oa / 12.0) + 0.1 * (ob / 12.0);
        out[0] = (float)loss;
    }
}

extern "C" void kernel_launch(void* const* d_in, const int* in_sizes, int n_in,
                              void* d_out, int out_size, void* d_ws, size_t ws_size,
                              hipStream_t stream)
{
    // ws layout: [partials: 512 KB][bufA][bufB][bufC], each buf VOL_N floats.
    double* partials = (double*)d_ws;
    float* bufA = (float*)((char*)d_ws + 512 * 1024);
    float* bufB = bufA + VOL_N;
    float* bufC = bufB + VOL_N;

    static const int pred_idx[6] = {0, 1, 3, 4, 6, 7};
    static const int gt_idx[6]   = {2, 2, 5, 5, 8, 8};
    static const int KD[6] = {1, 1, 3, 5, 7, 9};
    static const int KH[6] = {1, 5, 13, 23, 31, 41};
    // KW == KH for all scales.

    dim3 blk(256);
    int triGrid = (VOL_N + 255) / 256;
    const int HW = DIMH * DIMW;

    for (int p = 0; p < 6; ++p) {
        const float* pred = (const float*)d_in[pred_idx[p]];
        const float* gt   = (const float*)d_in[gt_idx[p]];
        for (int s = 0; s < 6; ++s) {
            int slot = (p * 6 + s) * 3;
            if (s == 0) {
                reduce_w<<<GRID_R, blk, 0, stream>>>(pred, gt, 1, 1.f, partials, slot);
                continue;
            }
            int kd = KD[s], kh = KH[s], kw = KH[s];
            float ihd = 1.f / (float)(kd * kd);
            float ihh = 1.f / (float)(kh * kh);
            float ihw = 1.f / (float)(kw * kw);

            const float* srcP = pred;
            if (kd > 1) {
                tri_conv<<<triGrid, blk, 0, stream>>>(srcP, bufA, VOL_N, DIMD, HW, kd, ihd);
                srcP = bufA;
            }
            tri_conv<<<triGrid, blk, 0, stream>>>(srcP, bufB, VOL_N, DIMH, DIMW, kh, ihh);

            const float* srcT = gt;
            if (kd > 1) {
                tri_conv<<<triGrid, blk, 0, stream>>>(srcT, bufA, VOL_N, DIMD, HW, kd, ihd);
                srcT = bufA;
            }
            tri_conv<<<triGrid, blk, 0, stream>>>(srcT, bufC, VOL_N, DIMH, DIMW, kh, ihh);

            reduce_w<<<GRID_R, blk, 0, stream>>>(bufB, bufC, kw, ihw, partials, slot);
        }
    }

    mono_reduce<<<GRID_R, blk, 0, stream>>>((const float*)d_in[9], partials);

    finalize<<<1, 128, 0, stream>>>(partials,
                                    (const float*)d_in[10], (const float*)d_in[11],
                                    (const float*)d_in[12], (const float*)d_in[13],
                                    (float*)d_out);
}

// Round 2
// 1151.972 us; speedup vs baseline: 7.2686x; 7.2686x over previous
//
#include <hip/hip_runtime.h>

// Criterion_BiNet — adjoint-reformulated multi-scale dice.
// Per (pair,scale): inter = p^T A^4 t  (A symmetric => (A^2 p)·(A^2 t) = p·A^4 t)
//                   sum_pp = p · (A^2 1)   [separable closed-form weights]
//                   sum_tt = t · (A^2 1)
// A^4 per axis = box filter applied 4x (zero-pad, /k each time) — exact.
// Slots: [0..35]  inter per (pair*6+scale)
//        [36..71] sum_p per (pair*6+scale)     (pred volumes in pair order)
//        [72..89] sum_t per (gt*6+scale)
//        [90]     monotonicity sum
#define DIMB 4
#define DIMD 28
#define DIMH 160
#define DIMW 160
#define HW   (DIMH * DIMW)
#define VOL_N (DIMB * DIMD * DIMH * DIMW)   // 2,867,200
#define GRID_P 640
#define NSLOTS 91
#define DICE_EPS 1e-7

__device__ __forceinline__ float u2f(int pos, int k, int L) {
    // (A^2 1)[pos] for a length-L axis, pool size k (odd), zero-pad.
    if (k == 1) return 1.f;
    int r = k >> 1;
    float s = 0.f;
    for (int j = max(pos - r, 0); j <= min(pos + r, L - 1); ++j)
        s += (float)(min(j + r, L - 1) - max(j - r, 0) + 1);
    return s / (float)(k * k);
}

__device__ __forceinline__ void block_reduce_write(double v, double* sh,
                                                   double* partials, int slot) {
    int t = threadIdx.x;
    sh[t] = v;
    __syncthreads();
    for (int off = 128; off > 0; off >>= 1) {
        if (t < off) sh[t] += sh[t + off];
        __syncthreads();
    }
    if (t == 0) partials[(size_t)slot * GRID_P + blockIdx.x] = sh[0];
    __syncthreads();
}

// K1: weighted sums of one raw volume against c_s = (A^2 1) for all 6 scales.
__global__ void wsum(const float* __restrict__ v, double* __restrict__ partials,
                     int slot_base)
{
    __shared__ float cD[6][DIMD], cH[6][DIMH];
    __shared__ double red[256];
    const int KD[6] = {1, 1, 3, 5, 7, 9};
    const int KH[6] = {1, 5, 13, 23, 31, 41};
    int t = threadIdx.x;
    for (int e = t; e < 6 * (DIMD + DIMH); e += 256) {
        int s = e / (DIMD + DIMH);
        int q = e % (DIMD + DIMH);
        if (q < DIMD) cD[s][q] = u2f(q, KD[s], DIMD);
        else          cH[s][q - DIMD] = u2f(q - DIMD, KH[s], DIMH);
    }
    __syncthreads();
    float acc[6] = {0.f, 0.f, 0.f, 0.f, 0.f, 0.f};
    for (int i = blockIdx.x * 256 + t; i < VOL_N; i += GRID_P * 256) {
        float x = v[i];
        int w = i % DIMW;
        int h = (i / DIMW) % DIMH;
        int d = (i / HW) % DIMD;
#pragma unroll
        for (int s = 0; s < 6; ++s)
            acc[s] += x * cD[s][d] * cH[s][h] * cH[s][w];
    }
    for (int s = 0; s < 6; ++s)
        block_reduce_write((double)acc[s], red, partials, slot_base + s);
}

// K2: box^4 along H (in -> out), tile = full H x 32 w's for one (b,d).
__global__ void hpool4(const float* __restrict__ in, float* __restrict__ out, int k)
{
    int blk = blockIdx.x;                 // 4*28*5
    int wt = blk % 5, bd = blk / 5;
    int wb = wt * 32;
    const float* base = in + (size_t)bd * HW;
    float* obase = out + (size_t)bd * HW;
    __shared__ float A[DIMH][32], B[DIMH][32];
    int t = threadIdx.x;
    int w = t % 32, c = t / 32;           // 8 chunks of 20 h's
    int h0 = c * 20;
    for (int h = h0; h < h0 + 20; ++h) A[h][w] = base[h * DIMW + wb + w];
    __syncthreads();
    int r = k >> 1;
    float invk = 1.f / (float)k;
    float (*src)[32] = A; float (*dst)[32] = B;
    for (int pass = 0; pass < 4; ++pass) {
        float s = 0.f;
        for (int j = max(h0 - r, 0); j <= min(h0 + r, DIMH - 1); ++j) s += src[j][w];
        dst[h0][w] = s * invk;
        for (int h = h0 + 1; h < h0 + 20; ++h) {
            int add = h + r, sub = h - r - 1;
            if (add < DIMH) s += src[add][w];
            if (sub >= 0)   s -= src[sub][w];
            dst[h][w] = s * invk;
        }
        __syncthreads();
        float (*tmp)[32] = src; src = dst; dst = tmp;
    }
    for (int h = h0; h < h0 + 20; ++h) obase[h * DIMW + wb + w] = src[h][w];
}

// K2b: box^4 along W, IN-PLACE, tile = 32 h's x full W for one (b,d).
__global__ void wpool4(float* __restrict__ buf, int k)
{
    int blk = blockIdx.x;                 // 4*28*5
    int ht = blk % 5, bd = blk / 5;
    float* base = buf + (size_t)bd * HW + (size_t)(ht * 32) * DIMW;
    __shared__ float A[32][DIMW + 1], B[32][DIMW + 1];
    int t = threadIdx.x;
    for (int e = t; e < 32 * DIMW; e += 256)
        A[e / DIMW][e % DIMW] = base[e];
    __syncthreads();
    int rr = t / 8, c = t % 8;
    int w0 = c * 20;
    int r = k >> 1;
    float invk = 1.f / (float)k;
    float (*src)[DIMW + 1] = A; float (*dst)[DIMW + 1] = B;
    for (int pass = 0; pass < 4; ++pass) {
        float s = 0.f;
        for (int j = max(w0 - r, 0); j <= min(w0 + r, DIMW - 1); ++j) s += src[rr][j];
        dst[rr][w0] = s * invk;
        for (int w = w0 + 1; w < w0 + 20; ++w) {
            int add = w + r, sub = w - r - 1;
            if (add < DIMW) s += src[rr][add];
            if (sub >= 0)   s -= src[rr][sub];
            dst[rr][w] = s * invk;
        }
        __syncthreads();
        float (*tmp)[DIMW + 1] = src; src = dst; dst = tmp;
    }
    for (int e = t; e < 32 * DIMW; e += 256)
        base[e] = src[e / DIMW][e % DIMW];
}

// K3: box^4 along D on the gt slab (in LDS) + fused product-reduce vs two preds.
// One block per (b,h); slab is (D=28) x (W=160).
__global__ void pair_reduce(const float* __restrict__ pc, const float* __restrict__ pp,
                            const float* __restrict__ tb, int kd,
                            double* __restrict__ partials, int slot_c, int slot_p)
{
    int blk = blockIdx.x;                 // 4*160
    int b = blk / DIMH, h = blk % DIMH;
    __shared__ float A[DIMD][DIMW], B[DIMD][DIMW];
    __shared__ double red[256];
    int t = threadIdx.x;
    for (int e = t; e < DIMD * DIMW; e += 256) {
        int d = e / DIMW, w = e % DIMW;
        A[d][w] = tb[(((size_t)b * DIMD + d) * DIMH + h) * DIMW + w];
    }
    __syncthreads();
    if (kd > 1) {
        int r = kd >> 1;
        float invk = 1.f / (float)kd;
        float (*src)[DIMW] = A; float (*dst)[DIMW] = B;
        for (int pass = 0; pass < 4; ++pass) {
            for (int e = t; e < DIMD * DIMW; e += 256) {
                int d = e / DIMW, w = e % DIMW;
                float s = 0.f;
                for (int j = max(d - r, 0); j <= min(d + r, DIMD - 1); ++j)
                    s += src[j][w];
                dst[d][w] = s * invk;
            }
            __syncthreads();
            float (*tmp)[DIMW] = src; src = dst; dst = tmp;
        }
        // 4 passes (even) -> result back in A
    }
    float aI = 0.f, aP = 0.f;
    for (int e = t; e < DIMD * DIMW; e += 256) {
        int d = e / DIMW, w = e % DIMW;
        size_t g = (((size_t)b * DIMD + d) * DIMH + h) * DIMW + w;
        float tv = A[d][w];
        aI += pc[g] * tv;
        aP += pp[g] * tv;
    }
    block_reduce_write((double)aI, red, partials, slot_c);
    block_reduce_write((double)aP, red, partials, slot_p);
}

__global__ void mono_reduce(const float* __restrict__ out6,
                            double* __restrict__ partials)
{
    const int DHW = DIMD * HW;            // 716,800
    const int N = DIMB * 5 * DHW;         // 14,336,000
    __shared__ double red[256];
    float acc = 0.f;
    for (int i = blockIdx.x * 256 + threadIdx.x; i < N; i += GRID_P * 256) {
        int rest = i % DHW;
        int tt = i / DHW;
        int c = tt % 5, b = tt / 5;
        const float* bp = out6 + (size_t)(b * 6 + c) * DHW + rest;
        float d = bp[DHW] - bp[0];
        acc += fabsf(d) - d;
    }
    block_reduce_write((double)acc, red, partials, 90);
}

__global__ void finalize(const double* __restrict__ partials,
                         const float* __restrict__ off_a,
                         const float* __restrict__ off_b,
                         const float* __restrict__ off_ta,
                         const float* __restrict__ off_tb,
                         float* __restrict__ out)
{
    __shared__ double S[NSLOTS];
    int t = threadIdx.x;
    if (t < NSLOTS) {
        double a = 0.0;
        for (int g = 0; g < GRID_P; ++g) a += partials[(size_t)t * GRID_P + g];
        S[t] = a;
    }
    __syncthreads();
    if (t == 0) {
        double loss = 0.0;
        for (int pair = 0; pair < 6; ++pair) {
            for (int s = 0; s < 6; ++s) {
                double inter = S[pair * 6 + s];
                double sp = S[36 + pair * 6 + s];
                double st = S[72 + (pair / 2) * 6 + s];
                loss += 0.2 * (1.0 - 2.0 * inter / (sp + st + DICE_EPS)) / 6.0;
            }
        }
        loss += 0.1 * (S[90] / (double)VOL_N);
        double oa = 0.0, ob = 0.0;
        for (int i = 0; i < 12; ++i) {
            oa += fabs((double)off_a[i] - (double)off_ta[i]);
            ob += fabs((double)off_b[i] - (double)off_tb[i]);
        }
        loss += 0.1 * (oa / 12.0) + 0.1 * (ob / 12.0);
        out[0] = (float)loss;
    }
}

extern "C" void kernel_launch(void* const* d_in, const int* in_sizes, int n_in,
                              void* d_out, int out_size, void* d_ws, size_t ws_size,
                              hipStream_t stream)
{
    double* partials = (double*)d_ws;                       // 91*640*8 = 466 KB
    float* bufs[3];
    bufs[0] = (float*)((char*)d_ws + 512 * 1024);
    bufs[1] = bufs[0] + VOL_N;
    bufs[2] = bufs[1] + VOL_N;

    const float* pred[6] = {(const float*)d_in[0], (const float*)d_in[1],
                            (const float*)d_in[3], (const float*)d_in[4],
                            (const float*)d_in[6], (const float*)d_in[7]};
    const float* gt[3] = {(const float*)d_in[2], (const float*)d_in[5],
                          (const float*)d_in[8]};
    static const int KD[6] = {1, 1, 3, 5, 7, 9};
    static const int KH[6] = {1, 5, 13, 23, 31, 41};

    dim3 blk(256);
    for (int p = 0; p < 6; ++p)
        wsum<<<GRID_P, blk, 0, stream>>>(pred[p], partials, 36 + p * 6);
    for (int g = 0; g < 3; ++g)
        wsum<<<GRID_P, blk, 0, stream>>>(gt[g], partials, 72 + g * 6);
    mono_reduce<<<GRID_P, blk, 0, stream>>>((const float*)d_in[9], partials);

    // scale 0: identity pooling
    for (int g = 0; g < 3; ++g)
        pair_reduce<<<GRID_P, blk, 0, stream>>>(pred[2 * g], pred[2 * g + 1], gt[g],
                                                1, partials,
                                                (2 * g) * 6 + 0, (2 * g + 1) * 6 + 0);
    for (int s = 1; s < 6; ++s) {
        for (int g = 0; g < 3; ++g) {
            hpool4<<<560, blk, 0, stream>>>(gt[g], bufs[g], KH[s]);
            wpool4<<<560, blk, 0, stream>>>(bufs[g], KH[s]);
            pair_reduce<<<GRID_P, blk, 0, stream>>>(pred[2 * g], pred[2 * g + 1],
                                                    bufs[g], KD[s], partials,
                                                    (2 * g) * 6 + s, (2 * g + 1) * 6 + s);
        }
    }

    finalize<<<1, 128, 0, stream>>>(partials,
                                    (const float*)d_in[10], (const float*)d_in[11],
                                    (const float*)d_in[12], (const float*)d_in[13],
                                    (float*)d_out);
}

// Round 3
// 364.543 us; speedup vs baseline: 22.9690x; 3.1600x over previous
//
#include <hip/hip_runtime.h>
#include <hip/hip_fp16.h>

// Criterion_BiNet — adjoint multi-scale dice, register-resident pooling.
// inter = p · (A^4 t); sum_p = p · (A^2 1); sum_t = t · (A^2 1).
// Stage 1 (hpool_all, per gt): H-axis box^4 for 5 scales, fp16 intermediates.
// Stage 2 (pair_reduce_all, per gt): W-box^4 (f2 LDS halo exchange) + D-box^4
//   (register columns) + inter dots + all weighted sums, one pass over preds.
// Slots: [0..35] inter (pair*6+s), [36..71] sum_p, [72..89] sum_t, [90] mono.

#define DIMB 4
#define DIMD 28
#define DIMH 160
#define DIMW 160
#define HW   (DIMH * DIMW)
#define DHW  (DIMD * HW)
#define VOL_N (DIMB * DHW)      // 2,867,200
#define GRID_P 640
#define NSLOTS 91
#define DICE_EPS 1e-7

__device__ __forceinline__ float u2f(int pos, int k, int L) {
    // (A^2 1)[pos]: zero-pad, count_include_pad avgpool applied twice.
    if (k == 1) return 1.f;
    int r = k >> 1;
    float s = 0.f;
    for (int j = max(pos - r, 0); j <= min(pos + r, L - 1); ++j)
        s += (float)(min(j + r, L - 1) - max(j - r, 0) + 1);
    return s / (float)(k * k);
}

__device__ __forceinline__ float wave_sum(float v) {
#pragma unroll
    for (int o = 1; o < 64; o <<= 1) v += __shfl_xor(v, o, 64);
    return v;
}

// ---------------- Stage 1: H-axis box^4, 5 scales, fp16 out ----------------
// grid 560 = B*D*5 wtiles, 128 threads: w = t&31, c = t>>5 (4 chunks of 40 h).
#define HSRC(j) ((j) < 20 ? lo[(j)] : ((j) < 60 ? own[(j)-20] : hi[(j)-60]))

template<int K>
__device__ __forceinline__ void hscale(const float* __restrict__ base,
                                       __half* __restrict__ ob,
                                       float (*X)[32], float (*Y)[32],
                                       int w, int h0)
{
    constexpr int R = K / 2;
    constexpr float INVK = 1.f / (float)K;
    float own[40];
#pragma unroll
    for (int i = 0; i < 40; ++i) {
        float v = base[(h0 + i) * DIMW + w];
        own[i] = v; X[h0 + i][w] = v;
    }
    __syncthreads();
    float (*src)[32] = X; float (*dst)[32] = Y;
#pragma unroll
    for (int pass = 0; pass < 4; ++pass) {
        float lo[20], hi[20];
#pragma unroll
        for (int i = 0; i < 20; ++i) {
            int hl = h0 - 20 + i;
            float vl = src[hl < 0 ? 0 : hl][w];
            lo[i] = (hl < 0) ? 0.f : vl;
            int hh = h0 + 40 + i;
            float vh = src[hh > (DIMH - 1) ? (DIMH - 1) : hh][w];
            hi[i] = (hh > (DIMH - 1)) ? 0.f : vh;
        }
        float out[40];
        float s = 0.f;
#pragma unroll
        for (int j = 20 - R; j <= 20 + R; ++j) s += HSRC(j);
        out[0] = s * INVK;
#pragma unroll
        for (int i = 1; i < 40; ++i) {
            s += HSRC(20 + i + R) - HSRC(20 + i - R - 1);
            out[i] = s * INVK;
        }
#pragma unroll
        for (int i = 0; i < 40; ++i) own[i] = out[i];
        if (pass < 3) {
#pragma unroll
            for (int i = 0; i < 40; ++i) dst[h0 + i][w] = own[i];
        }
        __syncthreads();
        float (*tm)[32] = src; src = dst; dst = tm;
    }
#pragma unroll
    for (int i = 0; i < 40; ++i) ob[(h0 + i) * DIMW + w] = __float2half(own[i]);
    __syncthreads();
}

__global__ __launch_bounds__(128) void hpool_all(const float* __restrict__ in,
                                                 __half* __restrict__ bufs)
{
    __shared__ float X[DIMH][32], Y[DIMH][32];
    int blk = blockIdx.x;             // 560 = 112 bd * 5 wtiles
    int wt = blk % 5, bd = blk / 5;
    int wb = wt * 32;
    const float* base = in + (size_t)bd * HW + wb;
    int t = threadIdx.x;
    int w = t & 31, c = t >> 5;
    int h0 = c * 40;
    size_t off = (size_t)bd * HW + wb;
    hscale<5> (base, bufs + 0 * (size_t)VOL_N + off, X, Y, w, h0);
    hscale<13>(base, bufs + 1 * (size_t)VOL_N + off, X, Y, w, h0);
    hscale<23>(base, bufs + 2 * (size_t)VOL_N + off, X, Y, w, h0);
    hscale<31>(base, bufs + 3 * (size_t)VOL_N + off, X, Y, w, h0);
    hscale<41>(base, bufs + 4 * (size_t)VOL_N + off, X, Y, w, h0);
}

// ---------------- Stage 2: W-box^4 + D-box^4 + dots + sums ----------------
#define WSRC(j) ((j) < 20 ? lo[(j)] : ((j) < 40 ? ox[(j)-20] : hi[(j)-40]))

template<int K>
__device__ __forceinline__ void wpass(float2 (*src)[81], float2 (*dst)[81],
                                      float (&ox)[20], int d, int q0, bool act)
{
    constexpr int R = K / 2;
    constexpr float INVK = 1.f / (float)K;
    if (act) {
        float lo[20], hi[20];
#pragma unroll
        for (int i = 0; i < 10; ++i) {
            int ql = q0 - 10 + i;
            float2 v = src[d][ql < 0 ? 0 : ql];
            lo[2*i]   = (ql < 0) ? 0.f : v.x;
            lo[2*i+1] = (ql < 0) ? 0.f : v.y;
            int qh = q0 + 10 + i;
            float2 v2 = src[d][qh > 79 ? 79 : qh];
            hi[2*i]   = (qh > 79) ? 0.f : v2.x;
            hi[2*i+1] = (qh > 79) ? 0.f : v2.y;
        }
        float out[20];
        float s = 0.f;
#pragma unroll
        for (int j = 20 - R; j <= 20 + R; ++j) s += WSRC(j);
        out[0] = s * INVK;
#pragma unroll
        for (int i = 1; i < 20; ++i) {
            s += WSRC(20 + i + R) - WSRC(20 + i - R - 1);
            out[i] = s * INVK;
        }
#pragma unroll
        for (int i = 0; i < 20; ++i) ox[i] = out[i];
#pragma unroll
        for (int i = 0; i < 10; ++i) dst[d][q0 + i] = make_float2(ox[2*i], ox[2*i+1]);
    }
    __syncthreads();
}

template<int K>
__device__ __forceinline__ void box4_col(float (&x)[28]) {
    constexpr int R = K / 2;
    constexpr float INVK = 1.f / (float)K;
#pragma unroll
    for (int p = 0; p < 4; ++p) {
        float y[28];
        float s = 0.f;
#pragma unroll
        for (int j = 0; j <= R; ++j) s += x[j];
        y[0] = s;
#pragma unroll
        for (int i = 1; i < 28; ++i) {
            if (i + R < 28) s += x[i + R];
            if (i - R - 1 >= 0) s -= x[i - R - 1];
            y[i] = s;
        }
#pragma unroll
        for (int i = 0; i < 28; ++i) x[i] = y[i] * INVK;
    }
}

template<int KH_, int KD_>
__device__ __forceinline__ void scale_body(const __half* __restrict__ bs,
    const float* __restrict__ pc, const float* __restrict__ pp,
    size_t base0, float2 (*X2)[81], float2 (*Y2)[81], int t,
    float& aIc, float& aIp)
{
    int d = t >> 3, c = t & 7, q0 = c * 10;
    bool act = (t < 224);
    for (int e = t; e < DIMD * 80; e += 256) {
        int dd = e / 80, q = e - dd * 80;
        __half2 hv = *(const __half2*)(bs + base0 + (size_t)dd * HW + (size_t)(2 * q));
        X2[dd][q] = __half22float2(hv);
    }
    __syncthreads();
    float ox[20];
    if (act) {
#pragma unroll
        for (int i = 0; i < 10; ++i) {
            float2 v = X2[d][q0 + i];
            ox[2*i] = v.x; ox[2*i+1] = v.y;
        }
    }
    wpass<KH_>(X2, Y2, ox, d, q0, act);
    wpass<KH_>(Y2, X2, ox, d, q0, act);
    wpass<KH_>(X2, Y2, ox, d, q0, act);
    wpass<KH_>(Y2, X2, ox, d, q0, act);   // final W-pooled in X2
    if (t < DIMW) {
        float col[28];
#pragma unroll
        for (int j = 0; j < 28; ++j) {
            float2 v = X2[j][t >> 1];
            col[j] = (t & 1) ? v.y : v.x;
        }
        if (KD_ > 1) box4_col<KD_>(col);
#pragma unroll
        for (int j = 0; j < 28; ++j) {
            size_t gi = base0 + (size_t)j * HW + (size_t)t;
            aIc += pc[gi] * col[j];
            aIp += pp[gi] * col[j];
        }
    }
    __syncthreads();   // X2 reads done before next scale's load
}

__global__ __launch_bounds__(256) void pair_reduce_all(
    const float* __restrict__ pc, const float* __restrict__ pp,
    const float* __restrict__ traw, const __half* __restrict__ bufs,
    double* __restrict__ partials, int g)
{
    __shared__ float2 X2[DIMD][81], Y2[DIMD][81];
    __shared__ float cD2s[6][DIMD], cW2s[6][DIMW];
    __shared__ float redS[4][32];
    int b = blockIdx.x / DIMH, h = blockIdx.x % DIMH;
    int t = threadIdx.x;
    const int KDa[6] = {1,1,3,5,7,9}, KHa[6] = {1,5,13,23,31,41};
    for (int e = t; e < 6 * DIMD; e += 256) {
        int s = e / DIMD, q = e - s * DIMD;
        cD2s[s][q] = u2f(q, KDa[s], DIMD);
    }
    for (int e = t; e < 6 * DIMW; e += 256) {
        int s = e / DIMW, q = e - s * DIMW;
        cW2s[s][q] = u2f(q, KHa[s], DIMW);
    }
    __syncthreads();
    size_t base0 = (size_t)b * DHW + (size_t)h * DIMW;

    float aI[12];
#pragma unroll
    for (int i = 0; i < 12; ++i) aI[i] = 0.f;

    // scale 0: identity pooling, raw gt
    if (t < DIMW) {
#pragma unroll
        for (int j = 0; j < DIMD; ++j) {
            size_t gi = base0 + (size_t)j * HW + (size_t)t;
            float tv = traw[gi];
            aI[0] += pc[gi] * tv;
            aI[6] += pp[gi] * tv;
        }
    }
    scale_body<5, 1>(bufs + 0 * (size_t)VOL_N, pc, pp, base0, X2, Y2, t, aI[1], aI[7]);
    scale_body<13,3>(bufs + 1 * (size_t)VOL_N, pc, pp, base0, X2, Y2, t, aI[2], aI[8]);
    scale_body<23,5>(bufs + 2 * (size_t)VOL_N, pc, pp, base0, X2, Y2, t, aI[3], aI[9]);
    scale_body<31,7>(bufs + 3 * (size_t)VOL_N, pc, pp, base0, X2, Y2, t, aI[4], aI[10]);
    scale_body<41,9>(bufs + 4 * (size_t)VOL_N, pc, pp, base0, X2, Y2, t, aI[5], aI[11]);

    // weighted sums (A^2 1 weights); cH2[s][h] factor applied at write.
    float aS[18];
#pragma unroll
    for (int i = 0; i < 18; ++i) aS[i] = 0.f;
    for (int e = t; e < DIMD * DIMW; e += 256) {
        int dd = e / DIMW, ww = e - dd * DIMW;
        size_t gi = base0 + (size_t)dd * HW + (size_t)ww;
        float vc = pc[gi], vp = pp[gi], vt = traw[gi];
#pragma unroll
        for (int s = 0; s < 6; ++s) {
            float e2 = cD2s[s][dd] * cW2s[s][ww];
            aS[s]      += vc * e2;
            aS[6 + s]  += vp * e2;
            aS[12 + s] += vt * e2;
        }
    }

    float vals[30];
#pragma unroll
    for (int i = 0; i < 12; ++i) vals[i] = aI[i];
#pragma unroll
    for (int i = 0; i < 18; ++i) vals[12 + i] = aS[i];
    int lane = t & 63, wid = t >> 6;
#pragma unroll
    for (int i = 0; i < 30; ++i) {
        float r = wave_sum(vals[i]);
        if (lane == 0) redS[wid][i] = r;
    }
    __syncthreads();
    if (t < 30) {
        double r = (double)redS[0][t] + (double)redS[1][t]
                 + (double)redS[2][t] + (double)redS[3][t];
        int slot; double fac = 1.0;
        if (t < 6) slot = (2 * g) * 6 + t;
        else if (t < 12) slot = (2 * g + 1) * 6 + (t - 6);
        else {
            int s = (t - 12) % 6;
            int kh = (s==0)?1:(s==1)?5:(s==2)?13:(s==3)?23:(s==4)?31:41;
            fac = (double)u2f(h, kh, DIMH);
            if (t < 18)      slot = 36 + (2 * g) * 6 + s;
            else if (t < 24) slot = 36 + (2 * g + 1) * 6 + s;
            else             slot = 72 + g * 6 + s;
        }
        partials[(size_t)slot * GRID_P + blockIdx.x] = r * fac;
    }
}

// ---------------- mono + finalize ----------------
__global__ __launch_bounds__(256) void mono_reduce(const float* __restrict__ o6,
                                                   double* __restrict__ partials)
{
    __shared__ float redS[4];
    const int N4 = VOL_N / 4;       // 716800
    const int PB = N4 / DIMB;       // 179200 (one channel in float4 units)
    float acc = 0.f;
    const float4* p = (const float4*)o6;
    for (int i = blockIdx.x * 256 + threadIdx.x; i < N4; i += GRID_P * 256) {
        int b = i / PB, r4 = i - b * PB;
        size_t a = (size_t)(b * 6) * PB + r4;
        float4 prev = p[a];
#pragma unroll
        for (int c = 1; c < 6; ++c) {
            float4 cur = p[a + (size_t)c * PB];
            acc += fmaxf(prev.x - cur.x, 0.f) + fmaxf(prev.y - cur.y, 0.f)
                 + fmaxf(prev.z - cur.z, 0.f) + fmaxf(prev.w - cur.w, 0.f);
            prev = cur;
        }
    }
    float r = wave_sum(acc * 2.f);
    int lane = threadIdx.x & 63, wid = threadIdx.x >> 6;
    if (lane == 0) redS[wid] = r;
    __syncthreads();
    if (threadIdx.x == 0)
        partials[(size_t)90 * GRID_P + blockIdx.x] =
            (double)redS[0] + (double)redS[1] + (double)redS[2] + (double)redS[3];
}

__global__ void finalize(const double* __restrict__ partials,
                         const float* __restrict__ off_a,
                         const float* __restrict__ off_b,
                         const float* __restrict__ off_ta,
                         const float* __restrict__ off_tb,
                         float* __restrict__ out)
{
    __shared__ double S[NSLOTS];
    int t = threadIdx.x;
    if (t < NSLOTS) {
        double a = 0.0;
        for (int gb = 0; gb < GRID_P; ++gb) a += partials[(size_t)t * GRID_P + gb];
        S[t] = a;
    }
    __syncthreads();
    if (t == 0) {
        double loss = 0.0;
        for (int pair = 0; pair < 6; ++pair) {
            for (int s = 0; s < 6; ++s) {
                double inter = S[pair * 6 + s];
                double sp = S[36 + pair * 6 + s];
                double st = S[72 + (pair / 2) * 6 + s];
                loss += 0.2 * (1.0 - 2.0 * inter / (sp + st + DICE_EPS)) / 6.0;
            }
        }
        loss += 0.1 * (S[90] / (double)VOL_N);
        double oa = 0.0, ob = 0.0;
        for (int i = 0; i < 12; ++i) {
            oa += fabs((double)off_a[i] - (double)off_ta[i]);
            ob += fabs((double)off_b[i] - (double)off_tb[i]);
        }
        loss += 0.1 * (oa / 12.0) + 0.1 * (ob / 12.0);
        out[0] = (float)loss;
    }
}

extern "C" void kernel_launch(void* const* d_in, const int* in_sizes, int n_in,
                              void* d_out, int out_size, void* d_ws, size_t ws_size,
                              hipStream_t stream)
{
    double* partials = (double*)d_ws;                   // 91*640*8 = 466 KB
    __half* bufs = (__half*)((char*)d_ws + 512 * 1024); // 5 * VOL_N fp16 = 28.7 MB

    const float* pred[6] = {(const float*)d_in[0], (const float*)d_in[1],
                            (const float*)d_in[3], (const float*)d_in[4],
                            (const float*)d_in[6], (const float*)d_in[7]};
    const float* gt[3] = {(const float*)d_in[2], (const float*)d_in[5],
                          (const float*)d_in[8]};

    for (int g = 0; g < 3; ++g) {
        hpool_all<<<560, 128, 0, stream>>>(gt[g], bufs);
        pair_reduce_all<<<GRID_P, 256, 0, stream>>>(pred[2*g], pred[2*g + 1],
                                                    gt[g], bufs, partials, g);
    }
    mono_reduce<<<GRID_P, 256, 0, stream>>>((const float*)d_in[9], partials);
    finalize<<<1, 128, 0, stream>>>(partials,
                                    (const float*)d_in[10], (const float*)d_in[11],
                                    (const float*)d_in[12], (const float*)d_in[13],
                                    (float*)d_out);
}

// Round 4
// 239.958 us; speedup vs baseline: 34.8944x; 1.5192x over previous
//
#include <hip/hip_runtime.h>
#include <hip/hip_fp16.h>

// Criterion_BiNet — adjoint multi-scale dice, scale-split pipeline.
// inter = p · (A^4 t); sum_p = p · (A^2 1); sum_t = t · (A^2 1).
// K1 hpool   (grid 2800, one (bd,wtile,scale)/block): H-axis box^4 -> fp16.
// K2 wd_dot  (grid 3200, one (b,h,scale)/block): W-box^4 (LDS, pad 161) +
//            D-box^4 (regs) + fused pred dots.
// K3 dot0_wsum (grid 640): scale-0 inters + all 18 closed-form weighted sums,
//            float4 streaming.
// Slots: [0..35] inter (pair*6+s), [36..71] sum_p, [72..89] sum_t, [90] mono.

#define DIMB 4
#define DIMD 28
#define DIMH 160
#define DIMW 160
#define HW   (DIMH * DIMW)
#define DHW  (DIMD * HW)
#define VOL_N (DIMB * DHW)      // 2,867,200
#define PGRID 640
#define NSLOTS 91
#define DICE_EPS 1e-7

__device__ __forceinline__ float u2f(int pos, int k, int L) {
    // (A^2 1)[pos]: zero-pad, count_include_pad avgpool applied twice.
    if (k == 1) return 1.f;
    int r = k >> 1;
    float s = 0.f;
    for (int j = max(pos - r, 0); j <= min(pos + r, L - 1); ++j)
        s += (float)(min(j + r, L - 1) - max(j - r, 0) + 1);
    return s / (float)(k * k);
}

__device__ __forceinline__ float wave_sum(float v) {
#pragma unroll
    for (int o = 1; o < 64; o <<= 1) v += __shfl_xor(v, o, 64);
    return v;
}

template<int K>
__device__ __forceinline__ void box4_col(float (&x)[28]) {
    constexpr int R = K / 2;
    constexpr float INVK = 1.f / (float)K;
#pragma unroll
    for (int p = 0; p < 4; ++p) {
        float y[28];
        float s = 0.f;
#pragma unroll
        for (int j = 0; j <= R; ++j) s += x[j];
        y[0] = s;
#pragma unroll
        for (int i = 1; i < 28; ++i) {
            if (i + R < 28) s += x[i + R];
            if (i - R - 1 >= 0) s -= x[i - R - 1];
            y[i] = s;
        }
#pragma unroll
        for (int i = 0; i < 28; ++i) x[i] = y[i] * INVK;
    }
}

// ---------------- K1: H-axis box^4, one scale per block ----------------
template<int K>
__device__ __forceinline__ void hscale1(const float* __restrict__ base,
                                        __half* __restrict__ ob,
                                        float (*S)[33], int w, int h0)
{
    constexpr int R = K / 2;
    constexpr float INVK = 1.f / (float)K;
    float own[40];
#pragma unroll
    for (int i = 0; i < 40; ++i) {
        float v = base[(h0 + i) * DIMW + w];
        own[i] = v; S[h0 + i][w] = v;
    }
    __syncthreads();
#pragma unroll
    for (int pass = 0; pass < 4; ++pass) {
        float lo[R], hi[R];
#pragma unroll
        for (int i = 0; i < R; ++i) {
            int hl = h0 - R + i;
            lo[i] = (hl < 0) ? 0.f : S[hl][w];
            int hh = h0 + 40 + i;
            hi[i] = (hh > DIMH - 1) ? 0.f : S[hh][w];
        }
#define HWIN(j) ((j) < R ? lo[(j)] : ((j) < R + 40 ? own[(j) - R] : hi[(j) - R - 40]))
        float out[40];
        float s = 0.f;
#pragma unroll
        for (int j = 0; j <= 2 * R; ++j) s += HWIN(j);
        out[0] = s * INVK;
#pragma unroll
        for (int i = 1; i < 40; ++i) {
            s += HWIN(i + 2 * R) - HWIN(i - 1);
            out[i] = s * INVK;
        }
#undef HWIN
#pragma unroll
        for (int i = 0; i < 40; ++i) own[i] = out[i];
        __syncthreads();
        if (pass < 3) {
#pragma unroll
            for (int i = 0; i < 40; ++i) S[h0 + i][w] = own[i];
        }
        __syncthreads();
    }
#pragma unroll
    for (int i = 0; i < 40; ++i) ob[(h0 + i) * DIMW + w] = __float2half(own[i]);
}

__global__ __launch_bounds__(128) void hpool(const float* __restrict__ in,
                                             __half* __restrict__ bufs)
{
    __shared__ float S[DIMH][33];
    int bx = blockIdx.x;                  // 2800 = 5 scales * 112 bd * 5 wtiles
    int sc = bx / 560, r = bx - sc * 560;
    int wt = r % 5, bd = r / 5;
    const float* base = in + (size_t)bd * HW + wt * 32;
    __half* ob = bufs + (size_t)sc * VOL_N + (size_t)bd * HW + wt * 32;
    int t = threadIdx.x, w = t & 31, h0 = (t >> 5) * 40;
    switch (sc) {
        case 0: hscale1<5> (base, ob, S, w, h0); break;
        case 1: hscale1<13>(base, ob, S, w, h0); break;
        case 2: hscale1<23>(base, ob, S, w, h0); break;
        case 3: hscale1<31>(base, ob, S, w, h0); break;
        default: hscale1<41>(base, ob, S, w, h0); break;
    }
}

// ---------------- K2: W-box^4 + D-box^4 + pred dot ----------------
template<int K, int KD>
__device__ __forceinline__ void wd_body(const __half* __restrict__ bs,
    const float* __restrict__ pc, const float* __restrict__ pp,
    float (*S)[161], int t, size_t base0, float& aIc, float& aIp)
{
    constexpr int R = K / 2;
    constexpr float INVK = 1.f / (float)K;
    for (int e = t; e < DIMD * 80; e += 256) {
        int d = e / 80, q = e - d * 80;
        __half2 hv = *(const __half2*)(bs + base0 + (size_t)d * HW + 2 * q);
        float2 f = __half22float2(hv);
        S[d][2 * q] = f.x; S[d][2 * q + 1] = f.y;
    }
    __syncthreads();
    int d = t >> 3, c = t & 7, q0 = c * 20;
    bool act = d < DIMD;
    float ox[20];
    if (act) {
#pragma unroll
        for (int i = 0; i < 20; ++i) ox[i] = S[d][q0 + i];
    }
#pragma unroll
    for (int pass = 0; pass < 4; ++pass) {
        if (act) {
            float lo[R], hi[R];
#pragma unroll
            for (int i = 0; i < R; ++i) {
                int ql = q0 - R + i;
                lo[i] = (ql < 0) ? 0.f : S[d][ql];
                int qh = q0 + 20 + i;
                hi[i] = (qh > DIMW - 1) ? 0.f : S[d][qh];
            }
#define WWIN(j) ((j) < R ? lo[(j)] : ((j) < R + 20 ? ox[(j) - R] : hi[(j) - R - 20]))
            float out[20];
            float s = 0.f;
#pragma unroll
            for (int j = 0; j <= 2 * R; ++j) s += WWIN(j);
            out[0] = s * INVK;
#pragma unroll
            for (int i = 1; i < 20; ++i) {
                s += WWIN(i + 2 * R) - WWIN(i - 1);
                out[i] = s * INVK;
            }
#undef WWIN
#pragma unroll
            for (int i = 0; i < 20; ++i) ox[i] = out[i];
        }
        __syncthreads();
        if (act) {
#pragma unroll
            for (int i = 0; i < 20; ++i) S[d][q0 + i] = ox[i];
        }
        __syncthreads();
    }
    if constexpr (KD > 1) {
        if (t < DIMW) {
            float col[28];
#pragma unroll
            for (int j = 0; j < 28; ++j) col[j] = S[j][t];
            box4_col<KD>(col);
#pragma unroll
            for (int j = 0; j < 28; ++j) S[j][t] = col[j];
        }
        __syncthreads();
    }
    for (int e = t; e < DIMD * DIMW; e += 256) {
        int dd = e / DIMW, w = e - dd * DIMW;
        size_t gi = base0 + (size_t)dd * HW + w;
        float tv = S[dd][w];
        aIc += pc[gi] * tv;
        aIp += pp[gi] * tv;
    }
}

__global__ __launch_bounds__(256) void wd_dot(const __half* __restrict__ bufs,
    const float* __restrict__ pc, const float* __restrict__ pp,
    double* __restrict__ partials, int g)
{
    __shared__ float S[DIMD][161];
    __shared__ float redS2[4][2];
    int bx = blockIdx.x;                  // 3200 = 5 scales * 640 bh
    int sc = bx / PGRID, bh = bx - sc * PGRID;
    int b = bh / DIMH, h = bh - b * DIMH;
    size_t base0 = (size_t)b * DHW + (size_t)h * DIMW;
    const __half* bs = bufs + (size_t)sc * VOL_N;
    int t = threadIdx.x;
    float aIc = 0.f, aIp = 0.f;
    switch (sc) {
        case 0: wd_body<5, 1> (bs, pc, pp, S, t, base0, aIc, aIp); break;
        case 1: wd_body<13, 3>(bs, pc, pp, S, t, base0, aIc, aIp); break;
        case 2: wd_body<23, 5>(bs, pc, pp, S, t, base0, aIc, aIp); break;
        case 3: wd_body<31, 7>(bs, pc, pp, S, t, base0, aIc, aIp); break;
        default: wd_body<41, 9>(bs, pc, pp, S, t, base0, aIc, aIp); break;
    }
    int lane = t & 63, wid = t >> 6;
    float r1 = wave_sum(aIc), r2 = wave_sum(aIp);
    if (lane == 0) { redS2[wid][0] = r1; redS2[wid][1] = r2; }
    __syncthreads();
    if (t < 2) {
        double r = (double)redS2[0][t] + (double)redS2[1][t]
                 + (double)redS2[2][t] + (double)redS2[3][t];
        int slot = (2 * g + t) * 6 + (sc + 1);
        partials[(size_t)slot * PGRID + bh] = r;
    }
}

// ---------------- K3: scale-0 inters + weighted sums, streaming ----------------
__global__ __launch_bounds__(256) void dot0_wsum(const float* __restrict__ pc,
    const float* __restrict__ pp, const float* __restrict__ tr,
    double* __restrict__ partials, int g)
{
    __shared__ float cD[6][DIMD], cL[6][DIMH];
    __shared__ float redS[4][20];
    const int KDa[6] = {1, 1, 3, 5, 7, 9};
    const int KHa[6] = {1, 5, 13, 23, 31, 41};
    int t = threadIdx.x;
    for (int e = t; e < 6 * DIMD; e += 256) {
        int s = e / DIMD, q = e - s * DIMD;
        cD[s][q] = u2f(q, KDa[s], DIMD);
    }
    for (int e = t; e < 6 * DIMH; e += 256) {
        int s = e / DIMH, q = e - s * DIMH;
        cL[s][q] = u2f(q, KHa[s], DIMH);
    }
    __syncthreads();
    float aI0c = 0.f, aI0p = 0.f;
    float aS[18];
#pragma unroll
    for (int i = 0; i < 18; ++i) aS[i] = 0.f;
    const float4* c4p = (const float4*)pc;
    const float4* p4p = (const float4*)pp;
    const float4* t4p = (const float4*)tr;
    const int N4 = VOL_N / 4;             // 716,800
    for (int i4 = blockIdx.x * 256 + t; i4 < N4; i4 += PGRID * 256) {
        int w4 = i4 % 40;
        int rest = i4 / 40;
        int h = rest % DIMH;
        int d = (rest / DIMH) % DIMD;
        float4 vc = c4p[i4], vp = p4p[i4], vt = t4p[i4];
        aI0c += vc.x * vt.x + vc.y * vt.y + vc.z * vt.z + vc.w * vt.w;
        aI0p += vp.x * vt.x + vp.y * vt.y + vp.z * vt.z + vp.w * vt.w;
#pragma unroll
        for (int s = 0; s < 6; ++s) {
            float cdh = cD[s][d] * cL[s][h];
            float w0 = cdh * cL[s][4 * w4 + 0];
            float w1 = cdh * cL[s][4 * w4 + 1];
            float w2 = cdh * cL[s][4 * w4 + 2];
            float w3 = cdh * cL[s][4 * w4 + 3];
            aS[s]      += w0 * vc.x + w1 * vc.y + w2 * vc.z + w3 * vc.w;
            aS[6 + s]  += w0 * vp.x + w1 * vp.y + w2 * vp.z + w3 * vp.w;
            aS[12 + s] += w0 * vt.x + w1 * vt.y + w2 * vt.z + w3 * vt.w;
        }
    }
    float vals[20];
    vals[0] = aI0c; vals[1] = aI0p;
#pragma unroll
    for (int i = 0; i < 18; ++i) vals[2 + i] = aS[i];
    int lane = t & 63, wid = t >> 6;
#pragma unroll
    for (int i = 0; i < 20; ++i) {
        float r = wave_sum(vals[i]);
        if (lane == 0) redS[wid][i] = r;
    }
    __syncthreads();
    if (t < 20) {
        double r = (double)redS[0][t] + (double)redS[1][t]
                 + (double)redS[2][t] + (double)redS[3][t];
        int slot;
        if (t == 0) slot = (2 * g) * 6;
        else if (t == 1) slot = (2 * g + 1) * 6;
        else {
            int i = t - 2, vv = i / 6, s = i % 6;
            slot = (vv == 0) ? 36 + (2 * g) * 6 + s
                 : (vv == 1) ? 36 + (2 * g + 1) * 6 + s
                             : 72 + g * 6 + s;
        }
        partials[(size_t)slot * PGRID + blockIdx.x] = r;
    }
}

// ---------------- mono + finalize ----------------
__global__ __launch_bounds__(256) void mono_reduce(const float* __restrict__ o6,
                                                   double* __restrict__ partials)
{
    __shared__ float redS[4];
    const int N4 = VOL_N / 4;
    const int PB = N4 / DIMB;
    float acc = 0.f;
    const float4* p = (const float4*)o6;
    for (int i = blockIdx.x * 256 + threadIdx.x; i < N4; i += PGRID * 256) {
        int b = i / PB, r4 = i - b * PB;
        size_t a = (size_t)(b * 6) * PB + r4;
        float4 prev = p[a];
#pragma unroll
        for (int c = 1; c < 6; ++c) {
            float4 cur = p[a + (size_t)c * PB];
            acc += fmaxf(prev.x - cur.x, 0.f) + fmaxf(prev.y - cur.y, 0.f)
                 + fmaxf(prev.z - cur.z, 0.f) + fmaxf(prev.w - cur.w, 0.f);
            prev = cur;
        }
    }
    float r = wave_sum(acc * 2.f);
    int lane = threadIdx.x & 63, wid = threadIdx.x >> 6;
    if (lane == 0) redS[wid] = r;
    __syncthreads();
    if (threadIdx.x == 0)
        partials[(size_t)90 * PGRID + blockIdx.x] =
            (double)redS[0] + (double)redS[1] + (double)redS[2] + (double)redS[3];
}

__global__ void finalize(const double* __restrict__ partials,
                         const float* __restrict__ off_a,
                         const float* __restrict__ off_b,
                         const float* __restrict__ off_ta,
                         const float* __restrict__ off_tb,
                         float* __restrict__ out)
{
    __shared__ double S[NSLOTS];
    int t = threadIdx.x;
    if (t < NSLOTS) {
        double a = 0.0;
        for (int gb = 0; gb < PGRID; ++gb) a += partials[(size_t)t * PGRID + gb];
        S[t] = a;
    }
    __syncthreads();
    if (t == 0) {
        double loss = 0.0;
        for (int pair = 0; pair < 6; ++pair) {
            for (int s = 0; s < 6; ++s) {
                double inter = S[pair * 6 + s];
                double sp = S[36 + pair * 6 + s];
                double st = S[72 + (pair / 2) * 6 + s];
                loss += 0.2 * (1.0 - 2.0 * inter / (sp + st + DICE_EPS)) / 6.0;
            }
        }
        loss += 0.1 * (S[90] / (double)VOL_N);
        double oa = 0.0, ob = 0.0;
        for (int i = 0; i < 12; ++i) {
            oa += fabs((double)off_a[i] - (double)off_ta[i]);
            ob += fabs((double)off_b[i] - (double)off_tb[i]);
        }
        loss += 0.1 * (oa / 12.0) + 0.1 * (ob / 12.0);
        out[0] = (float)loss;
    }
}

extern "C" void kernel_launch(void* const* d_in, const int* in_sizes, int n_in,
                              void* d_out, int out_size, void* d_ws, size_t ws_size,
                              hipStream_t stream)
{
    double* partials = (double*)d_ws;                   // 91*640*8 = 466 KB
    __half* bufs = (__half*)((char*)d_ws + 512 * 1024); // 5 * VOL_N fp16 = 28.7 MB

    const float* pred[6] = {(const float*)d_in[0], (const float*)d_in[1],
                            (const float*)d_in[3], (const float*)d_in[4],
                            (const float*)d_in[6], (const float*)d_in[7]};
    const float* gt[3] = {(const float*)d_in[2], (const float*)d_in[5],
                          (const float*)d_in[8]};

    for (int g = 0; g < 3; ++g) {
        hpool<<<2800, 128, 0, stream>>>(gt[g], bufs);
        wd_dot<<<3200, 256, 0, stream>>>(bufs, pred[2*g], pred[2*g + 1], partials, g);
        dot0_wsum<<<PGRID, 256, 0, stream>>>(pred[2*g], pred[2*g + 1], gt[g],
                                             partials, g);
    }
    mono_reduce<<<PGRID, 256, 0, stream>>>((const float*)d_in[9], partials);
    finalize<<<1, 128, 0, stream>>>(partials,
                                    (const float*)d_in[10], (const float*)d_in[11],
                                    (const float*)d_in[12], (const float*)d_in[13],
                                    (float*)d_out);
}

// Round 5
// 165.976 us; speedup vs baseline: 50.4481x; 1.4457x over previous
//
#include <hip/hip_runtime.h>
#include <hip/hip_fp16.h>

// Criterion_BiNet — adjoint multi-scale dice, wave-local (shuffle-halo) pooling.
// inter = p · (A^4 t); sum_p = p · (A^2 1); sum_t = t · (A^2 1).
// K1 hpool : H-axis box^4, chunk=40/lane, halo via __shfl(l±16). No LDS/syncs.
// K2 wd_dot: W-box^4 chunk=20/lane, halo via __shfl(l±1); one LDS store, D-box^4
//            in regs (transpose via LDS), float4 pred dot. 3 syncs total.
// K3 dot0_wsum: scale-0 inters + 18 closed-form weighted sums, float4 streaming.
// Slots: [0..35] inter (pair*6+s), [36..71] sum_p, [72..89] sum_t, [90] mono.

#define DIMB 4
#define DIMD 28
#define DIMH 160
#define DIMW 160
#define HW   (DIMH * DIMW)
#define DHW  (DIMD * HW)
#define VOL_N (DIMB * DHW)      // 2,867,200
#define PGRID 640
#define NSLOTS 91
#define DICE_EPS 1e-7

__device__ __forceinline__ float u2f(int pos, int k, int L) {
    if (k == 1) return 1.f;
    int r = k >> 1;
    float s = 0.f;
    for (int j = max(pos - r, 0); j <= min(pos + r, L - 1); ++j)
        s += (float)(min(j + r, L - 1) - max(j - r, 0) + 1);
    return s / (float)(k * k);
}

__device__ __forceinline__ float wave_sum(float v) {
#pragma unroll
    for (int o = 1; o < 64; o <<= 1) v += __shfl_xor(v, o, 64);
    return v;
}

template<int K>
__device__ __forceinline__ void box4_col(float (&x)[28]) {
    constexpr int R = K / 2;
    constexpr float INVK = 1.f / (float)K;
#pragma unroll
    for (int p = 0; p < 4; ++p) {
        float y[28];
        float s = 0.f;
#pragma unroll
        for (int j = 0; j <= R; ++j) s += x[j];
        y[0] = s;
#pragma unroll
        for (int i = 1; i < 28; ++i) {
            if (i + R < 28) s += x[i + R];
            if (i - R - 1 >= 0) s -= x[i - R - 1];
            y[i] = s;
        }
#pragma unroll
        for (int i = 0; i < 28; ++i) x[i] = y[i] * INVK;
    }
}

// ---------------- K1: H-axis box^4, shuffle halos, no LDS ----------------
// 128 threads: lane l: chunk c = l>>4 (4 chunks of 40 h), w = v*16 + (l&15).
template<int K>
__device__ __forceinline__ void hbody(const float* __restrict__ base,
                                      __half* __restrict__ ob, int t)
{
    constexpr int R = K / 2;
    constexpr float INVK = 1.f / (float)K;
    int l = t & 63, v = t >> 6;
    int c = l >> 4;
    int wl = v * 16 + (l & 15);
    int h0 = c * 40;
    float ox[40];
#pragma unroll
    for (int i = 0; i < 40; ++i) ox[i] = base[(h0 + i) * DIMW + wl];
#pragma unroll
    for (int pass = 0; pass < 4; ++pass) {
        float lo[R], hi[R];
#pragma unroll
        for (int i = 0; i < R; ++i) {
            float a = __shfl(ox[40 - R + i], l - 16, 64);
            lo[i] = (c == 0) ? 0.f : a;
            float b = __shfl(ox[i], l + 16, 64);
            hi[i] = (c == 3) ? 0.f : b;
        }
#define HWIN(j) ((j) < R ? lo[(j)] : ((j) < R + 40 ? ox[(j) - R] : hi[(j) - R - 40]))
        float out[40];
        float s = 0.f;
#pragma unroll
        for (int j = 0; j <= 2 * R; ++j) s += HWIN(j);
        out[0] = s * INVK;
#pragma unroll
        for (int i = 1; i < 40; ++i) {
            s += HWIN(i + 2 * R) - HWIN(i - 1);
            out[i] = s * INVK;
        }
#undef HWIN
#pragma unroll
        for (int i = 0; i < 40; ++i) ox[i] = out[i];
    }
#pragma unroll
    for (int i = 0; i < 40; ++i) ob[(h0 + i) * DIMW + wl] = __float2half(ox[i]);
}

__device__ __forceinline__ void hpool_run(const float* in, __half* ob5, int sc,
                                          int bd, int wt, int t)
{
    const float* base = in + (size_t)bd * HW + wt * 32;
    __half* ob = ob5 + (size_t)sc * VOL_N + (size_t)bd * HW + wt * 32;
    switch (sc) {
        case 0: hbody<5>(base, ob, t); break;
        case 1: hbody<13>(base, ob, t); break;
        case 2: hbody<23>(base, ob, t); break;
        case 3: hbody<31>(base, ob, t); break;
        default: hbody<41>(base, ob, t); break;
    }
}

__global__ __launch_bounds__(128) void hpool_one(const float* __restrict__ in,
                                                 __half* __restrict__ bufs)
{
    int bx = blockIdx.x;              // 2800 = 5 sc * 112 bd * 5 wt
    int sc = bx / 560, r = bx - sc * 560;
    hpool_run(in, bufs, sc, r / 5, r % 5, threadIdx.x);
}

__global__ __launch_bounds__(128) void hpool_all(const float* __restrict__ in0,
    const float* __restrict__ in1, const float* __restrict__ in2,
    __half* __restrict__ bufs)
{
    int bx = blockIdx.x;              // 8400
    int g = bx / 2800, r0 = bx - g * 2800;
    int sc = r0 / 560, r = r0 - sc * 560;
    const float* in = (g == 0) ? in0 : (g == 1) ? in1 : in2;
    hpool_run(in, bufs + (size_t)g * 5 * VOL_N, sc, r / 5, r % 5, threadIdx.x);
}

// ---------------- K2: W-box^4 (shuffle) + D-box^4 + float4 dot ----------------
template<int K, int KD>
__device__ __forceinline__ void wd_body(const __half* __restrict__ bs,
    const float* __restrict__ pc, const float* __restrict__ pp,
    float (*S)[161], int t, size_t base0, float& aIc, float& aIp)
{
    constexpr int R = K / 2;
    constexpr float INVK = 1.f / (float)K;
    int l = t & 63, v = t >> 6;
    int rr = v * 7 + (l >> 3);        // row 0..27 (l<56)
    int c = l & 7;
    bool act = (l < 56);
    float ox[20];
#pragma unroll
    for (int i = 0; i < 20; ++i) ox[i] = 0.f;
    if (act) {
        const __half* hp = bs + base0 + (size_t)rr * HW + c * 20;
#pragma unroll
        for (int q = 0; q < 5; ++q) {
            uint2 u = *(const uint2*)(hp + 4 * q);
            __half2 a = *reinterpret_cast<__half2*>(&u.x);
            __half2 b = *reinterpret_cast<__half2*>(&u.y);
            float2 fa = __half22float2(a), fb = __half22float2(b);
            ox[4 * q + 0] = fa.x; ox[4 * q + 1] = fa.y;
            ox[4 * q + 2] = fb.x; ox[4 * q + 3] = fb.y;
        }
    }
#pragma unroll
    for (int pass = 0; pass < 4; ++pass) {
        float lo[R], hi[R];
#pragma unroll
        for (int i = 0; i < R; ++i) {
            float a = __shfl(ox[20 - R + i], l - 1, 64);
            lo[i] = (c == 0) ? 0.f : a;
            float b = __shfl(ox[i], l + 1, 64);
            hi[i] = (c == 7) ? 0.f : b;
        }
#define WWIN(j) ((j) < R ? lo[(j)] : ((j) < R + 20 ? ox[(j) - R] : hi[(j) - R - 20]))
        float out[20];
        float s = 0.f;
#pragma unroll
        for (int j = 0; j <= 2 * R; ++j) s += WWIN(j);
        out[0] = s * INVK;
#pragma unroll
        for (int i = 1; i < 20; ++i) {
            s += WWIN(i + 2 * R) - WWIN(i - 1);
            out[i] = s * INVK;
        }
#undef WWIN
#pragma unroll
        for (int i = 0; i < 20; ++i) ox[i] = out[i];
    }
    if (act) {
#pragma unroll
        for (int i = 0; i < 20; ++i) S[rr][c * 20 + i] = ox[i];
    }
    __syncthreads();
    if constexpr (KD > 1) {
        if (t < DIMW) {
            float col[28];
#pragma unroll
            for (int j = 0; j < 28; ++j) col[j] = S[j][t];
            box4_col<KD>(col);
#pragma unroll
            for (int j = 0; j < 28; ++j) S[j][t] = col[j];
        }
        __syncthreads();
    }
    for (int e4 = t; e4 < DIMD * 40; e4 += 256) {
        int dd = e4 / 40, w4 = e4 - dd * 40;
        size_t gb = base0 + (size_t)dd * HW + 4 * w4;
        float4 vc = *(const float4*)(pc + gb);
        float4 vp = *(const float4*)(pp + gb);
        float t0 = S[dd][4 * w4 + 0], t1 = S[dd][4 * w4 + 1];
        float t2 = S[dd][4 * w4 + 2], t3 = S[dd][4 * w4 + 3];
        aIc += vc.x * t0 + vc.y * t1 + vc.z * t2 + vc.w * t3;
        aIp += vp.x * t0 + vp.y * t1 + vp.z * t2 + vp.w * t3;
    }
}

__device__ __forceinline__ void wd_run(const __half* bs, const float* pc,
    const float* pp, double* partials, int g, int sc, int bh)
{
    __shared__ float S[DIMD][161];
    __shared__ float redS2[4][2];
    int b = bh / DIMH, h = bh - b * DIMH;
    size_t base0 = (size_t)b * DHW + (size_t)h * DIMW;
    int t = threadIdx.x;
    float aIc = 0.f, aIp = 0.f;
    switch (sc) {
        case 0: wd_body<5, 1>(bs, pc, pp, S, t, base0, aIc, aIp); break;
        case 1: wd_body<13, 3>(bs, pc, pp, S, t, base0, aIc, aIp); break;
        case 2: wd_body<23, 5>(bs, pc, pp, S, t, base0, aIc, aIp); break;
        case 3: wd_body<31, 7>(bs, pc, pp, S, t, base0, aIc, aIp); break;
        default: wd_body<41, 9>(bs, pc, pp, S, t, base0, aIc, aIp); break;
    }
    float r1 = wave_sum(aIc), r2 = wave_sum(aIp);
    int lane = t & 63, wid = t >> 6;
    if (lane == 0) { redS2[wid][0] = r1; redS2[wid][1] = r2; }
    __syncthreads();
    if (t < 2) {
        double rs = (double)redS2[0][t] + (double)redS2[1][t]
                  + (double)redS2[2][t] + (double)redS2[3][t];
        partials[(size_t)((2 * g + t) * 6 + sc + 1) * PGRID + bh] = rs;
    }
}

__global__ __launch_bounds__(256) void wd_one(const __half* __restrict__ bufs,
    const float* __restrict__ pc, const float* __restrict__ pp,
    double* __restrict__ partials, int g)
{
    int bx = blockIdx.x;              // 3200 = 5 sc * 640 bh
    int sc = bx / PGRID, bh = bx - sc * PGRID;
    wd_run(bufs + (size_t)sc * VOL_N, pc, pp, partials, g, sc, bh);
}

__global__ __launch_bounds__(256) void wd_all(const __half* __restrict__ bufs,
    const float* __restrict__ pc0, const float* __restrict__ pp0,
    const float* __restrict__ pc1, const float* __restrict__ pp1,
    const float* __restrict__ pc2, const float* __restrict__ pp2,
    double* __restrict__ partials)
{
    int bx = blockIdx.x;              // 9600
    int g = bx / 3200, r = bx - g * 3200;
    int sc = r / PGRID, bh = r - sc * PGRID;
    const float* pc = (g == 0) ? pc0 : (g == 1) ? pc1 : pc2;
    const float* pp = (g == 0) ? pp0 : (g == 1) ? pp1 : pp2;
    wd_run(bufs + (size_t)(g * 5 + sc) * VOL_N, pc, pp, partials, g, sc, bh);
}

// ---------------- K3: scale-0 inters + weighted sums (all 3 g's) ----------------
__global__ __launch_bounds__(256) void dot0_all(const float* __restrict__ pc0,
    const float* __restrict__ pp0, const float* __restrict__ tr0,
    const float* __restrict__ pc1, const float* __restrict__ pp1,
    const float* __restrict__ tr1, const float* __restrict__ pc2,
    const float* __restrict__ pp2, const float* __restrict__ tr2,
    double* __restrict__ partials)
{
    __shared__ float cD[6][DIMD], cL[6][DIMH];
    __shared__ float redS[4][20];
    const int KDa[6] = {1, 1, 3, 5, 7, 9};
    const int KHa[6] = {1, 5, 13, 23, 31, 41};
    int t = threadIdx.x;
    int g = blockIdx.x / PGRID, blk = blockIdx.x - g * PGRID;
    const float* pc = (g == 0) ? pc0 : (g == 1) ? pc1 : pc2;
    const float* pp = (g == 0) ? pp0 : (g == 1) ? pp1 : pp2;
    const float* tr = (g == 0) ? tr0 : (g == 1) ? tr1 : tr2;
    for (int e = t; e < 6 * DIMD; e += 256) {
        int s = e / DIMD, q = e - s * DIMD;
        cD[s][q] = u2f(q, KDa[s], DIMD);
    }
    for (int e = t; e < 6 * DIMH; e += 256) {
        int s = e / DIMH, q = e - s * DIMH;
        cL[s][q] = u2f(q, KHa[s], DIMH);
    }
    __syncthreads();
    float aI0c = 0.f, aI0p = 0.f;
    float aS[18];
#pragma unroll
    for (int i = 0; i < 18; ++i) aS[i] = 0.f;
    const float4* c4p = (const float4*)pc;
    const float4* p4p = (const float4*)pp;
    const float4* t4p = (const float4*)tr;
    const int N4 = VOL_N / 4;
    for (int i4 = blk * 256 + t; i4 < N4; i4 += PGRID * 256) {
        int w4 = i4 % 40;
        int rest = i4 / 40;
        int h = rest % DIMH;
        int d = (rest / DIMH) % DIMD;
        float4 vc = c4p[i4], vp = p4p[i4], vt = t4p[i4];
        aI0c += vc.x * vt.x + vc.y * vt.y + vc.z * vt.z + vc.w * vt.w;
        aI0p += vp.x * vt.x + vp.y * vt.y + vp.z * vt.z + vp.w * vt.w;
#pragma unroll
        for (int s = 0; s < 6; ++s) {
            float cdh = cD[s][d] * cL[s][h];
            float w0 = cdh * cL[s][4 * w4 + 0];
            float w1 = cdh * cL[s][4 * w4 + 1];
            float w2 = cdh * cL[s][4 * w4 + 2];
            float w3 = cdh * cL[s][4 * w4 + 3];
            aS[s]      += w0 * vc.x + w1 * vc.y + w2 * vc.z + w3 * vc.w;
            aS[6 + s]  += w0 * vp.x + w1 * vp.y + w2 * vp.z + w3 * vp.w;
            aS[12 + s] += w0 * vt.x + w1 * vt.y + w2 * vt.z + w3 * vt.w;
        }
    }
    float vals[20];
    vals[0] = aI0c; vals[1] = aI0p;
#pragma unroll
    for (int i = 0; i < 18; ++i) vals[2 + i] = aS[i];
    int lane = t & 63, wid = t >> 6;
#pragma unroll
    for (int i = 0; i < 20; ++i) {
        float r = wave_sum(vals[i]);
        if (lane == 0) redS[wid][i] = r;
    }
    __syncthreads();
    if (t < 20) {
        double r = (double)redS[0][t] + (double)redS[1][t]
                 + (double)redS[2][t] + (double)redS[3][t];
        int slot;
        if (t == 0) slot = (2 * g) * 6;
        else if (t == 1) slot = (2 * g + 1) * 6;
        else {
            int i = t - 2, vv = i / 6, s = i % 6;
            slot = (vv == 0) ? 36 + (2 * g) * 6 + s
                 : (vv == 1) ? 36 + (2 * g + 1) * 6 + s
                             : 72 + g * 6 + s;
        }
        partials[(size_t)slot * PGRID + blk] = r;
    }
}

// ---------------- mono + finalize ----------------
__global__ __launch_bounds__(256) void mono_reduce(const float* __restrict__ o6,
                                                   double* __restrict__ partials)
{
    __shared__ float redS[4];
    const int N4 = VOL_N / 4;
    const int PB = N4 / DIMB;
    float acc = 0.f;
    const float4* p = (const float4*)o6;
    for (int i = blockIdx.x * 256 + threadIdx.x; i < N4; i += PGRID * 256) {
        int b = i / PB, r4 = i - b * PB;
        size_t a = (size_t)(b * 6) * PB + r4;
        float4 prev = p[a];
#pragma unroll
        for (int c = 1; c < 6; ++c) {
            float4 cur = p[a + (size_t)c * PB];
            acc += fmaxf(prev.x - cur.x, 0.f) + fmaxf(prev.y - cur.y, 0.f)
                 + fmaxf(prev.z - cur.z, 0.f) + fmaxf(prev.w - cur.w, 0.f);
            prev = cur;
        }
    }
    float r = wave_sum(acc * 2.f);
    int lane = threadIdx.x & 63, wid = threadIdx.x >> 6;
    if (lane == 0) redS[wid] = r;
    __syncthreads();
    if (threadIdx.x == 0)
        partials[(size_t)90 * PGRID + blockIdx.x] =
            (double)redS[0] + (double)redS[1] + (double)redS[2] + (double)redS[3];
}

__global__ void finalize(const double* __restrict__ partials,
                         const float* __restrict__ off_a,
                         const float* __restrict__ off_b,
                         const float* __restrict__ off_ta,
                         const float* __restrict__ off_tb,
                         float* __restrict__ out)
{
    __shared__ double S[NSLOTS];
    int t = threadIdx.x;
    if (t < NSLOTS) {
        double a = 0.0;
        for (int gb = 0; gb < PGRID; ++gb) a += partials[(size_t)t * PGRID + gb];
        S[t] = a;
    }
    __syncthreads();
    if (t == 0) {
        double loss = 0.0;
        for (int pair = 0; pair < 6; ++pair) {
            for (int s = 0; s < 6; ++s) {
                double inter = S[pair * 6 + s];
                double sp = S[36 + pair * 6 + s];
                double st = S[72 + (pair / 2) * 6 + s];
                loss += 0.2 * (1.0 - 2.0 * inter / (sp + st + DICE_EPS)) / 6.0;
            }
        }
        loss += 0.1 * (S[90] / (double)VOL_N);
        double oa = 0.0, ob = 0.0;
        for (int i = 0; i < 12; ++i) {
            oa += fabs((double)off_a[i] - (double)off_ta[i]);
            ob += fabs((double)off_b[i] - (double)off_tb[i]);
        }
        loss += 0.1 * (oa / 12.0) + 0.1 * (ob / 12.0);
        out[0] = (float)loss;
    }
}

extern "C" void kernel_launch(void* const* d_in, const int* in_sizes, int n_in,
                              void* d_out, int out_size, void* d_ws, size_t ws_size,
                              hipStream_t stream)
{
    double* partials = (double*)d_ws;                   // 91*640*8 = 466 KB
    __half* bufs = (__half*)((char*)d_ws + 512 * 1024);

    const float* pred[6] = {(const float*)d_in[0], (const float*)d_in[1],
                            (const float*)d_in[3], (const float*)d_in[4],
                            (const float*)d_in[6], (const float*)d_in[7]};
    const float* gt[3] = {(const float*)d_in[2], (const float*)d_in[5],
                          (const float*)d_in[8]};

    size_t need = 512 * 1024 + (size_t)15 * VOL_N * sizeof(__half); // 86.5 MB
    if (ws_size >= need) {
        hpool_all<<<8400, 128, 0, stream>>>(gt[0], gt[1], gt[2], bufs);
        wd_all<<<9600, 256, 0, stream>>>(bufs, pred[0], pred[1], pred[2],
                                         pred[3], pred[4], pred[5], partials);
    } else {
        for (int g = 0; g < 3; ++g) {
            hpool_one<<<2800, 128, 0, stream>>>(gt[g], bufs);
            wd_one<<<3200, 256, 0, stream>>>(bufs, pred[2 * g], pred[2 * g + 1],
                                             partials, g);
        }
    }
    dot0_all<<<3 * PGRID, 256, 0, stream>>>(pred[0], pred[1], gt[0],
                                            pred[2], pred[3], gt[1],
                                            pred[4], pred[5], gt[2], partials);
    mono_reduce<<<PGRID, 256, 0, stream>>>((const float*)d_in[9], partials);
    finalize<<<1, 128, 0, stream>>>(partials,
                                    (const float*)d_in[10], (const float*)d_in[11],
                                    (const float*)d_in[12], (const float*)d_in[13],
                                    (float*)d_out);
}

// Round 6
// 139.762 us; speedup vs baseline: 59.9103x; 1.1876x over previous
//
#include <hip/hip_runtime.h>
#include <hip/hip_fp16.h>

// Criterion_BiNet — adjoint multi-scale dice, 2-unit prefetch pipeline.
// inter = p · (A^4 t); sum_p = p · (A^2 1); sum_t = t · (A^2 1).
// K1 hpool_mono: H-axis box^4 (shuffle halos, 2 units/block) + mono blocks.
// K2 wd5: per (group,g,b,h): W-box^4 (shuffle) + D-box^4 + dots; groups:
//         {raw dot0+18 wsums, k41}, {k5, k31}, {k13, k23}; reg prefetch.
// K3 fin_pre: 91-slot parallel partial reduce.  K4 finalize: scalar combine.
// Slots: [0..35] inter (pair*6+s), [36..71] sum_p, [72..89] sum_t, [90] mono.

#define DIMB 4
#define DIMD 28
#define DIMH 160
#define DIMW 160
#define HW   (DIMH * DIMW)
#define DHW  (DIMD * HW)
#define VOL_N (DIMB * DHW)      // 2,867,200
#define PGRID 640
#define NSLOTS 91
#define DICE_EPS 1e-7

__device__ __forceinline__ float u2f(int pos, int k, int L) {
    if (k == 1) return 1.f;
    int r = k >> 1;
    float s = 0.f;
    for (int j = max(pos - r, 0); j <= min(pos + r, L - 1); ++j)
        s += (float)(min(j + r, L - 1) - max(j - r, 0) + 1);
    return s / (float)(k * k);
}

__device__ __forceinline__ float wave_sum(float v) {
#pragma unroll
    for (int o = 1; o < 64; o <<= 1) v += __shfl_xor(v, o, 64);
    return v;
}

template<int K>
__device__ __forceinline__ void box4_col(float (&x)[28]) {
    constexpr int R = K / 2;
    constexpr float INVK = 1.f / (float)K;
#pragma unroll
    for (int p = 0; p < 4; ++p) {
        float y[28];
        float s = 0.f;
#pragma unroll
        for (int j = 0; j <= R; ++j) s += x[j];
        y[0] = s;
#pragma unroll
        for (int i = 1; i < 28; ++i) {
            if (i + R < 28) s += x[i + R];
            if (i - R - 1 >= 0) s -= x[i - R - 1];
            y[i] = s;
        }
#pragma unroll
        for (int i = 0; i < 28; ++i) x[i] = y[i] * INVK;
    }
}

// ---------------- K1a: H-axis box^4, shuffle halos, no LDS ----------------
template<int K>
__device__ __forceinline__ void hbody(const float* __restrict__ base,
                                      __half* __restrict__ ob, int t)
{
    constexpr int R = K / 2;
    constexpr float INVK = 1.f / (float)K;
    int l = t & 63, v = t >> 6;
    int c = l >> 4;
    int wl = v * 16 + (l & 15);
    int h0 = c * 40;
    float ox[40];
#pragma unroll
    for (int i = 0; i < 40; ++i) ox[i] = base[(h0 + i) * DIMW + wl];
#pragma unroll
    for (int pass = 0; pass < 4; ++pass) {
        float lo[R], hi[R];
#pragma unroll
        for (int i = 0; i < R; ++i) {
            float a = __shfl(ox[40 - R + i], l - 16, 64);
            lo[i] = (c == 0) ? 0.f : a;
            float b = __shfl(ox[i], l + 16, 64);
            hi[i] = (c == 3) ? 0.f : b;
        }
#define HWIN(j) ((j) < R ? lo[(j)] : ((j) < R + 40 ? ox[(j) - R] : hi[(j) - R - 40]))
        float out[40];
        float s = 0.f;
#pragma unroll
        for (int j = 0; j <= 2 * R; ++j) s += HWIN(j);
        out[0] = s * INVK;
#pragma unroll
        for (int i = 1; i < 40; ++i) {
            s += HWIN(i + 2 * R) - HWIN(i - 1);
            out[i] = s * INVK;
        }
#undef HWIN
#pragma unroll
        for (int i = 0; i < 40; ++i) ox[i] = out[i];
    }
#pragma unroll
    for (int i = 0; i < 40; ++i) ob[(h0 + i) * DIMW + wl] = __float2half(ox[i]);
}

__device__ __forceinline__ void hpool_run(const float* in, __half* ob5, int sc,
                                          int bd, int wt, int t)
{
    const float* base = in + (size_t)bd * HW + wt * 32;
    __half* ob = ob5 + (size_t)sc * VOL_N + (size_t)bd * HW + wt * 32;
    switch (sc) {
        case 0: hbody<5>(base, ob, t); break;
        case 1: hbody<13>(base, ob, t); break;
        case 2: hbody<23>(base, ob, t); break;
        case 3: hbody<31>(base, ob, t); break;
        default: hbody<41>(base, ob, t); break;
    }
}

// K1: blocks [0,4200): 2 hpool units each; [4200,4840): mono reduction.
__global__ __launch_bounds__(256) void hpool_mono(const float* __restrict__ g0,
    const float* __restrict__ g1, const float* __restrict__ g2,
    const float* __restrict__ o6, __half* __restrict__ bufs,
    double* __restrict__ partials)
{
    __shared__ float redSm[4];
    int bx = blockIdx.x;
    if (bx < 4200) {
        int u = bx * 2 + (threadIdx.x >> 7);   // 8400 units = 3g*5sc*112bd*5wt
        int tt = threadIdx.x & 127;
        int gg = u / 2800, r0 = u - gg * 2800;
        int sc = r0 / 560, r = r0 - sc * 560;
        const float* in = (gg == 0) ? g0 : (gg == 1) ? g1 : g2;
        hpool_run(in, bufs + (size_t)gg * 5 * VOL_N, sc, r / 5, r % 5, tt);
    } else {
        int mb = bx - 4200;
        const int N4 = VOL_N / 4, PB = N4 / DIMB;
        float acc = 0.f;
        const float4* p = (const float4*)o6;
        for (int i = mb * 256 + threadIdx.x; i < N4; i += PGRID * 256) {
            int b = i / PB, r4 = i - b * PB;
            size_t a = (size_t)(b * 6) * PB + r4;
            float4 prev = p[a];
#pragma unroll
            for (int cc = 1; cc < 6; ++cc) {
                float4 cur = p[a + (size_t)cc * PB];
                acc += fmaxf(prev.x - cur.x, 0.f) + fmaxf(prev.y - cur.y, 0.f)
                     + fmaxf(prev.z - cur.z, 0.f) + fmaxf(prev.w - cur.w, 0.f);
                prev = cur;
            }
        }
        float rv = wave_sum(acc * 2.f);
        int lane = threadIdx.x & 63, wid = threadIdx.x >> 6;
        if (lane == 0) redSm[wid] = rv;
        __syncthreads();
        if (threadIdx.x == 0)
            partials[(size_t)90 * PGRID + mb] =
                (double)redSm[0] + redSm[1] + redSm[2] + redSm[3];
    }
}

// ---------------- K2: W-box^4 (shuffle) + D-box^4 + float4 dot ----------------
template<int K, int KD>
__device__ __forceinline__ void scale_work(const uint2 (&rg)[5],
    float (*S)[164], int t, int l, int c, int rr, bool act,
    const float* __restrict__ pc, const float* __restrict__ pp,
    size_t base0, float& aic, float& aip)
{
    constexpr int R = K / 2;
    constexpr float INVK = 1.f / (float)K;
    float ox[20];
#pragma unroll
    for (int i = 0; i < 20; ++i) ox[i] = 0.f;
    if (act) {
#pragma unroll
        for (int q = 0; q < 5; ++q) {
            __half2 a = *reinterpret_cast<const __half2*>(&rg[q].x);
            __half2 b = *reinterpret_cast<const __half2*>(&rg[q].y);
            float2 fa = __half22float2(a), fb = __half22float2(b);
            ox[4*q+0] = fa.x; ox[4*q+1] = fa.y;
            ox[4*q+2] = fb.x; ox[4*q+3] = fb.y;
        }
    }
#pragma unroll
    for (int pass = 0; pass < 4; ++pass) {
        float lo[R], hi[R];
#pragma unroll
        for (int i = 0; i < R; ++i) {
            float a = __shfl(ox[20 - R + i], l - 1, 64);
            lo[i] = (c == 0) ? 0.f : a;
            float b = __shfl(ox[i], l + 1, 64);
            hi[i] = (c == 7) ? 0.f : b;
        }
#define WWIN(j) ((j) < R ? lo[(j)] : ((j) < R + 20 ? ox[(j) - R] : hi[(j) - R - 20]))
        float out[20];
        float s = 0.f;
#pragma unroll
        for (int j = 0; j <= 2 * R; ++j) s += WWIN(j);
        out[0] = s * INVK;
#pragma unroll
        for (int i = 1; i < 20; ++i) {
            s += WWIN(i + 2 * R) - WWIN(i - 1);
            out[i] = s * INVK;
        }
#undef WWIN
#pragma unroll
        for (int i = 0; i < 20; ++i) ox[i] = out[i];
    }
    if (act) {
#pragma unroll
        for (int i = 0; i < 20; ++i) S[rr][c * 20 + i] = ox[i];
    }
    __syncthreads();
    if constexpr (KD > 1) {
        if (t < DIMW) {
            float col[28];
#pragma unroll
            for (int j = 0; j < 28; ++j) col[j] = S[j][t];
            box4_col<KD>(col);
#pragma unroll
            for (int j = 0; j < 28; ++j) S[j][t] = col[j];
        }
        __syncthreads();
    }
    for (int e4 = t; e4 < 280; e4 += 256) {
        int dd = e4 / 40, w4 = e4 - dd * 40;
        size_t gb = base0 + (size_t)dd * HW + 4 * w4;
        float4 vc = *(const float4*)(pc + gb);
        float4 vp = *(const float4*)(pp + gb);
        float t0 = S[dd][4*w4], t1 = S[dd][4*w4+1];
        float t2 = S[dd][4*w4+2], t3 = S[dd][4*w4+3];
        aic += vc.x*t0 + vc.y*t1 + vc.z*t2 + vc.w*t3;
        aip += vp.x*t0 + vp.y*t1 + vp.z*t2 + vp.w*t3;
    }
    __syncthreads();
}

__global__ __launch_bounds__(256) void wd5(const __half* __restrict__ bufs,
    const float* __restrict__ pc0, const float* __restrict__ pp0,
    const float* __restrict__ pc1, const float* __restrict__ pp1,
    const float* __restrict__ pc2, const float* __restrict__ pp2,
    const float* __restrict__ tr0, const float* __restrict__ tr1,
    const float* __restrict__ tr2, double* __restrict__ partials)
{
    __shared__ float S[DIMD][164];
    __shared__ float cD[6][DIMD], cW[6][DIMW];
    __shared__ float redS[4][22];
    int bx = blockIdx.x;                 // 5760 = 3 grp * 3 g * 640 bh
    int grp = bx / 1920, r = bx - grp * 1920;
    int g = r / PGRID, bh = r - g * PGRID;
    int b = bh / DIMH, h = bh - b * DIMH;
    size_t base0 = (size_t)b * DHW + (size_t)h * DIMW;
    const float* pc = (g == 0) ? pc0 : (g == 1) ? pc1 : pc2;
    const float* pp = (g == 0) ? pp0 : (g == 1) ? pp1 : pp2;
    int t = threadIdx.x;
    int l = t & 63;
    int rr = (t >> 6) * 7 + (l >> 3), c = l & 7;
    bool act = l < 56;
    const __half* tb = bufs + (size_t)g * 5 * VOL_N + base0
                     + (size_t)rr * HW + c * 20;
    int wid = t >> 6;

    if (grp == 0) {
        const float* tr = (g == 0) ? tr0 : (g == 1) ? tr1 : tr2;
        const int KDa[6] = {1, 1, 3, 5, 7, 9};
        const int KHa[6] = {1, 5, 13, 23, 31, 41};
        for (int e = t; e < 6 * DIMD; e += 256) {
            int s = e / DIMD, q = e - s * DIMD;
            cD[s][q] = u2f(q, KDa[s], DIMD);
        }
        for (int e = t; e < 6 * DIMW; e += 256) {
            int s = e / DIMW, q = e - s * DIMW;
            cW[s][q] = u2f(q, KHa[s], DIMW);
        }
        __syncthreads();
        uint2 rA[5];
        if (act) {
            const __half* hp = tb + (size_t)4 * VOL_N;   // k=41 tile
#pragma unroll
            for (int q = 0; q < 5; ++q) rA[q] = *(const uint2*)(hp + 4 * q);
        }
        float vals[22];
#pragma unroll
        for (int i = 0; i < 22; ++i) vals[i] = 0.f;
        for (int e4 = t; e4 < 280; e4 += 256) {
            int dd = e4 / 40, w4 = e4 - dd * 40;
            size_t gb = base0 + (size_t)dd * HW + 4 * w4;
            float4 vt = *(const float4*)(tr + gb);
            float4 vc = *(const float4*)(pc + gb);
            float4 vp = *(const float4*)(pp + gb);
            vals[0] += vc.x*vt.x + vc.y*vt.y + vc.z*vt.z + vc.w*vt.w;
            vals[1] += vp.x*vt.x + vp.y*vt.y + vp.z*vt.z + vp.w*vt.w;
#pragma unroll
            for (int s = 0; s < 6; ++s) {
                float cdh = cD[s][dd];
                float w0 = cdh * cW[s][4*w4+0], w1 = cdh * cW[s][4*w4+1];
                float w2 = cdh * cW[s][4*w4+2], w3 = cdh * cW[s][4*w4+3];
                vals[2+s]  += w0*vc.x + w1*vc.y + w2*vc.z + w3*vc.w;
                vals[8+s]  += w0*vp.x + w1*vp.y + w2*vp.z + w3*vp.w;
                vals[14+s] += w0*vt.x + w1*vt.y + w2*vt.z + w3*vt.w;
            }
        }
        scale_work<41, 9>(rA, S, t, l, c, rr, act, pc, pp, base0,
                          vals[20], vals[21]);
#pragma unroll
        for (int i = 0; i < 22; ++i) {
            float rv = wave_sum(vals[i]);
            if (l == 0) redS[wid][i] = rv;
        }
        __syncthreads();
        if (t < 22) {
            double rv = (double)redS[0][t] + redS[1][t] + redS[2][t] + redS[3][t];
            int slot; double fac = 1.0;
            if (t == 0) slot = (2 * g) * 6;
            else if (t == 1) slot = (2 * g + 1) * 6;
            else if (t < 20) {
                int i = t - 2, vv = i / 6, s = i % 6;
                fac = (double)cW[s][h];
                slot = (vv == 0) ? 36 + (2 * g) * 6 + s
                     : (vv == 1) ? 36 + (2 * g + 1) * 6 + s
                                 : 72 + g * 6 + s;
            }
            else if (t == 20) slot = (2 * g) * 6 + 5;
            else slot = (2 * g + 1) * 6 + 5;
            partials[(size_t)slot * PGRID + bh] = rv * fac;
        }
    } else {
        uint2 rA[5], rB[5];
        int scA = (grp == 1) ? 0 : 1;    // k=5  / k=13
        int scB = (grp == 1) ? 3 : 2;    // k=31 / k=23
        if (act) {
            const __half* ha = tb + (size_t)scA * VOL_N;
            const __half* hb = tb + (size_t)scB * VOL_N;
#pragma unroll
            for (int q = 0; q < 5; ++q) rA[q] = *(const uint2*)(ha + 4 * q);
#pragma unroll
            for (int q = 0; q < 5; ++q) rB[q] = *(const uint2*)(hb + 4 * q);
        }
        float vals[4] = {0.f, 0.f, 0.f, 0.f};
        if (grp == 1) {
            scale_work<5, 1>(rA, S, t, l, c, rr, act, pc, pp, base0, vals[0], vals[1]);
            scale_work<31, 7>(rB, S, t, l, c, rr, act, pc, pp, base0, vals[2], vals[3]);
        } else {
            scale_work<13, 3>(rA, S, t, l, c, rr, act, pc, pp, base0, vals[0], vals[1]);
            scale_work<23, 5>(rB, S, t, l, c, rr, act, pc, pp, base0, vals[2], vals[3]);
        }
#pragma unroll
        for (int i = 0; i < 4; ++i) {
            float rv = wave_sum(vals[i]);
            if (l == 0) redS[wid][i] = rv;
        }
        __syncthreads();
        if (t < 4) {
            double rv = (double)redS[0][t] + redS[1][t] + redS[2][t] + redS[3][t];
            int sd = (t < 2) ? ((grp == 1) ? 1 : 2) : ((grp == 1) ? 4 : 3);
            int slot = (2 * g + (t & 1)) * 6 + sd;
            partials[(size_t)slot * PGRID + bh] = rv;
        }
    }
}

// ---------------- K3/K4: reduction tail ----------------
__global__ __launch_bounds__(64) void fin_pre(const double* __restrict__ partials,
                                              double* __restrict__ ssum)
{
    int slot = blockIdx.x, t = threadIdx.x;
    double a = 0.0;
    for (int i = t; i < PGRID; i += 64) a += partials[(size_t)slot * PGRID + i];
#pragma unroll
    for (int o = 1; o < 64; o <<= 1) a += __shfl_xor(a, o, 64);
    if (t == 0) ssum[slot] = a;
}

__global__ void finalize(const double* __restrict__ ssum,
                         const float* __restrict__ off_a,
                         const float* __restrict__ off_b,
                         const float* __restrict__ off_ta,
                         const float* __restrict__ off_tb,
                         float* __restrict__ out)
{
    if (threadIdx.x == 0) {
        double loss = 0.0;
        for (int pair = 0; pair < 6; ++pair) {
            for (int s = 0; s < 6; ++s) {
                double inter = ssum[pair * 6 + s];
                double sp = ssum[36 + pair * 6 + s];
                double st = ssum[72 + (pair / 2) * 6 + s];
                loss += 0.2 * (1.0 - 2.0 * inter / (sp + st + DICE_EPS)) / 6.0;
            }
        }
        loss += 0.1 * (ssum[90] / (double)VOL_N);
        double oa = 0.0, ob = 0.0;
        for (int i = 0; i < 12; ++i) {
            oa += fabs((double)off_a[i] - (double)off_ta[i]);
            ob += fabs((double)off_b[i] - (double)off_tb[i]);
        }
        loss += 0.1 * (oa / 12.0) + 0.1 * (ob / 12.0);
        out[0] = (float)loss;
    }
}

extern "C" void kernel_launch(void* const* d_in, const int* in_sizes, int n_in,
                              void* d_out, int out_size, void* d_ws, size_t ws_size,
                              hipStream_t stream)
{
    double* partials = (double*)d_ws;                   // 91*640*8 = 465,920 B
    double* ssum = partials + (size_t)NSLOTS * PGRID;   // +91*8, still < 512 KB
    __half* bufs = (__half*)((char*)d_ws + 512 * 1024); // 15 * VOL_N fp16 = 86 MB

    const float* pred[6] = {(const float*)d_in[0], (const float*)d_in[1],
                            (const float*)d_in[3], (const float*)d_in[4],
                            (const float*)d_in[6], (const float*)d_in[7]};
    const float* gt[3] = {(const float*)d_in[2], (const float*)d_in[5],
                          (const float*)d_in[8]};

    hpool_mono<<<4840, 256, 0, stream>>>(gt[0], gt[1], gt[2],
                                         (const float*)d_in[9], bufs, partials);
    wd5<<<5760, 256, 0, stream>>>(bufs, pred[0], pred[1], pred[2], pred[3],
                                  pred[4], pred[5], gt[0], gt[1], gt[2], partials);
    fin_pre<<<NSLOTS, 64, 0, stream>>>(partials, ssum);
    finalize<<<1, 64, 0, stream>>>(ssum,
                                   (const float*)d_in[10], (const float*)d_in[11],
                                   (const float*)d_in[12], (const float*)d_in[13],
                                   (float*)d_out);
}